// Round 9
// baseline (141.269 us; speedup 1.0000x reference)
//
#include <hip/hip_runtime.h>
#include <hip/hip_bf16.h>
#include <cstddef>

#define N_FEATS 64
#define NBKT_SHIFT 8      // coarse bucket = dst >> 8  (256 nodes per bucket)
#define EPB1 4096         // edges per phase-1 block
// NOTE: packing below requires N <= 65536 (src fits u16). Here N = 50000.

// round-to-nearest-even f32 -> bf16 bits
__device__ __forceinline__ unsigned f2bf(float f) {
    unsigned x = __float_as_uint(f);
    return (x + 0x7fffu + ((x >> 16) & 1u)) >> 16;
}

// ---------------------------------------------------------------------------
// Phase 1a: per-block coarse histogram -> H[bucket][block]  (bucket-major)
// ---------------------------------------------------------------------------
__global__ __launch_bounds__(256) void k_chist(const int* __restrict__ dst,
                                               int* __restrict__ H,
                                               int nEdges, int nbkt, int nb1) {
    __shared__ int lh[256];
    int tid = threadIdx.x, blk = blockIdx.x;
    lh[tid] = 0;
    __syncthreads();
    int base = blk * EPB1;
    #pragma unroll
    for (int j = 0; j < EPB1 / 256; ++j) {
        int e = base + j * 256 + tid;
        if (e < nEdges) atomicAdd(&lh[((unsigned)dst[e]) >> NBKT_SHIFT], 1);
    }
    __syncthreads();
    if (tid < nbkt) H[tid * nb1 + blk] = lh[tid];
}

// ---------------------------------------------------------------------------
// Scan: per-block partials, then per-block exclusive scan deriving its own
// base from the partials (no root kernel).
// ---------------------------------------------------------------------------
__global__ __launch_bounds__(256) void k_partial(const int* __restrict__ in,
                                                 int* __restrict__ partials, int n) {
    __shared__ int sdata[256];
    int tid = threadIdx.x;
    int i = blockIdx.x * 256 + tid;
    sdata[tid] = (i < n) ? in[i] : 0;
    __syncthreads();
    for (int s = 128; s > 0; s >>= 1) {
        if (tid < s) sdata[tid] += sdata[tid + s];
        __syncthreads();
    }
    if (tid == 0) partials[blockIdx.x] = sdata[0];
}

__global__ __launch_bounds__(256) void k_offsets2(const int* __restrict__ in,
                                                  const int* __restrict__ partials,
                                                  int* __restrict__ out, int n) {
    __shared__ int sdata[256];
    __shared__ int sbase[256];
    int tid = threadIdx.x;
    int i = blockIdx.x * 256 + tid;
    int b = 0;
    for (int j = tid; j < blockIdx.x; j += 256) b += partials[j];
    sbase[tid] = b;
    int v = (i < n) ? in[i] : 0;
    sdata[tid] = v;
    __syncthreads();
    for (int s = 128; s > 0; s >>= 1) {
        if (tid < s) sbase[tid] += sbase[tid + s];
        __syncthreads();
    }
    for (int d = 1; d < 256; d <<= 1) {
        int t = (tid >= d) ? sdata[tid - d] : 0;
        __syncthreads();
        sdata[tid] += t;
        __syncthreads();
    }
    int excl = sdata[tid] - v + sbase[0];
    if (i < n) out[i] = excl;
}

// ---------------------------------------------------------------------------
// Phase 1b: multisplit -> packed pairs (src<<8 | dst&255), grouped by coarse
// bucket; per-(bucket,block) cells contiguous; cursors in LDS.
// ---------------------------------------------------------------------------
__global__ __launch_bounds__(256) void k_split(const int* __restrict__ src,
                                               const int* __restrict__ dst,
                                               const int* __restrict__ HO,
                                               unsigned* __restrict__ pairs,
                                               int nEdges, int nbkt, int nb1) {
    __shared__ int cur[256];
    int tid = threadIdx.x, blk = blockIdx.x;
    if (tid < nbkt) cur[tid] = HO[tid * nb1 + blk];
    __syncthreads();
    int base = blk * EPB1;
    #pragma unroll
    for (int j = 0; j < EPB1 / 256; ++j) {
        int e = base + j * 256 + tid;
        if (e < nEdges) {
            unsigned d = (unsigned)dst[e];
            int pos = atomicAdd(&cur[d >> NBKT_SHIFT], 1);
            pairs[pos] = ((unsigned)src[e] << 8) | (d & 255u);
        }
    }
}

// ---------------------------------------------------------------------------
// Phase 2: one block per coarse bucket; counting sort by dst&255 in LDS.
// Emits counts[], offsets[], sorted_src[] (u16) — block-region-local writes.
// ---------------------------------------------------------------------------
__global__ __launch_bounds__(256) void k_fsort(const unsigned* __restrict__ pairs,
                                               const int* __restrict__ HO,
                                               int* __restrict__ counts,
                                               int* __restrict__ offsets,
                                               unsigned short* __restrict__ sorted_src,
                                               int nEdges, int nNodes,
                                               int nbkt, int nb1) {
    __shared__ int cnt[256];
    __shared__ int scanbuf[256];
    __shared__ int cur[256];
    int tid = threadIdx.x, b = blockIdx.x;
    int bStart = HO[b * nb1];
    int bEnd = (b + 1 < nbkt) ? HO[(b + 1) * nb1] : nEdges;
    cnt[tid] = 0;
    __syncthreads();
    for (int e = bStart + tid; e < bEnd; e += 256) {
        atomicAdd(&cnt[pairs[e] & 255u], 1);
    }
    __syncthreads();
    int v = cnt[tid];
    scanbuf[tid] = v;
    __syncthreads();
    for (int d = 1; d < 256; d <<= 1) {
        int t = (tid >= d) ? scanbuf[tid - d] : 0;
        __syncthreads();
        scanbuf[tid] += t;
        __syncthreads();
    }
    int excl = scanbuf[tid] - v;
    int node = (b << NBKT_SHIFT) + tid;
    if (node < nNodes) { counts[node] = v; offsets[node] = bStart + excl; }
    cur[tid] = bStart + excl;
    __syncthreads();
    for (int e = bStart + tid; e < bEnd; e += 256) {
        unsigned pr = pairs[e];
        int pos = atomicAdd(&cur[pr & 255u], 1);
        sorted_src[pos] = (unsigned short)(pr >> 8);
    }
}

// ---------------------------------------------------------------------------
// Dense projections  u = X@Wl1 (bf16),  v = X@Wr1 + b (f32).
// block = 256 thr = 4 waves over 64 nodes; wave w: matrix m=w>>1, half
// f0=(w&1)*32. 32 accumulators/thread -> 3128 waves total (~4/SIMD).
// ---------------------------------------------------------------------------
__global__ __launch_bounds__(256) void k_gemm(
        const float* __restrict__ x,
        const float* __restrict__ Wl1,
        const float* __restrict__ bl1,
        const float* __restrict__ Wr1,
        unsigned* __restrict__ u,      // bf16 pairs: N x 32 uints
        float* __restrict__ v,
        int nNodes) {
    __shared__ float sWl[64 * 64];
    __shared__ float sWr[64 * 64];
    __shared__ float sb[64];

    int tid = threadIdx.x;
    for (int i = tid; i < 1024; i += 256) {
        ((float4*)sWl)[i] = ((const float4*)Wl1)[i];
        ((float4*)sWr)[i] = ((const float4*)Wr1)[i];
    }
    if (tid < 64) sb[tid] = bl1[tid];
    __syncthreads();

    int w = tid >> 6, lane = tid & 63;
    int m  = w >> 1;            // 0 -> u (Wl), 1 -> v (Wr)
    int f0 = (w & 1) * 32;      // output half
    int node = blockIdx.x * 64 + lane;
    bool valid = (node < nNodes);

    float4 vx[16];
    const float4* xv4 = (const float4*)x;
    if (valid) {
        #pragma unroll
        for (int j = 0; j < 16; ++j) vx[j] = xv4[(size_t)node * 16 + j];
    } else {
        #pragma unroll
        for (int j = 0; j < 16; ++j) vx[j] = make_float4(0.f, 0.f, 0.f, 0.f);
    }

    const float* W = (m == 0) ? sWl : sWr;
    float acc[32];
    #pragma unroll
    for (int j = 0; j < 32; ++j) acc[j] = (m == 1) ? sb[f0 + j] : 0.f;

    #pragma unroll
    for (int k4 = 0; k4 < 16; ++k4) {
        float4 xq = vx[k4];
        #pragma unroll
        for (int kk = 0; kk < 4; ++kk) {
            int k = k4 * 4 + kk;
            float xk = (kk == 0) ? xq.x : (kk == 1) ? xq.y : (kk == 2) ? xq.z : xq.w;
            #pragma unroll
            for (int j4 = 0; j4 < 8; ++j4) {
                float4 wv = *(const float4*)&W[k * 64 + f0 + j4 * 4];
                acc[j4 * 4 + 0] += xk * wv.x;
                acc[j4 * 4 + 1] += xk * wv.y;
                acc[j4 * 4 + 2] += xk * wv.z;
                acc[j4 * 4 + 3] += xk * wv.w;
            }
        }
    }
    if (!valid) return;
    if (m == 0) {
        #pragma unroll
        for (int j = 0; j < 4; ++j) {
            uint4 sv;
            sv.x = f2bf(acc[j*8+0]) | (f2bf(acc[j*8+1]) << 16);
            sv.y = f2bf(acc[j*8+2]) | (f2bf(acc[j*8+3]) << 16);
            sv.z = f2bf(acc[j*8+4]) | (f2bf(acc[j*8+5]) << 16);
            sv.w = f2bf(acc[j*8+6]) | (f2bf(acc[j*8+7]) << 16);
            ((uint4*)u)[(size_t)node * 8 + (f0 >> 3) + j] = sv;
        }
    } else {
        #pragma unroll
        for (int j = 0; j < 8; ++j) {
            float4 t;
            t.x = acc[j*4+0]; t.y = acc[j*4+1];
            t.z = acc[j*4+2]; t.w = acc[j*4+3];
            ((float4*)v)[(size_t)node * 16 + (f0 >> 2) + j] = t;
        }
    }
}

// ---------------------------------------------------------------------------
// h = mean-gather(u: bf16) + v;  p = h@Wl2; q = h@Wr2.
// 1 node/wave; 16 lanes x 8B per u-row, 4 edge-groups in parallel.
// ---------------------------------------------------------------------------
__global__ __launch_bounds__(256) void k_gather1(
        const unsigned* __restrict__ u,
        const float* __restrict__ v,
        const int* __restrict__ counts,
        const int* __restrict__ offsets,
        const unsigned short* __restrict__ sorted_src,
        const float* __restrict__ Wl2,
        const float* __restrict__ Wr2,
        float* __restrict__ p,
        float* __restrict__ q,
        int nNodes) {
    __shared__ float sWl2[64 * 9];
    __shared__ float sWr2[64 * 9];
    __shared__ float sh[4][64];

    int tid = threadIdx.x;
    for (int i = tid; i < 64 * 8; i += 256) {
        int k = i >> 3, c = i & 7;
        sWl2[k * 9 + c] = Wl2[i];
        sWr2[k * 9 + c] = Wr2[i];
    }
    __syncthreads();

    int slot = tid >> 6;
    int f    = tid & 63;
    int g    = f >> 4;
    int t4   = f & 15;
    const uint2* uv2 = (const uint2*)u;

    int node = blockIdx.x * 4 + slot;
    if (node >= nNodes) return;
    int cnt = counts[node];
    int off = offsets[node];

    float ax = 0.f, ay = 0.f, az = 0.f, aw = 0.f;
    int id = (g < cnt) ? (int)sorted_src[off + g] : -1;
    for (int base = 0; base < cnt; base += 4) {
        int en  = base + 4 + g;
        int idn = (en < cnt) ? (int)sorted_src[off + en] : -1;
        if (id >= 0) {
            uint2 r = uv2[(size_t)id * 16 + t4];
            ax += __uint_as_float(r.x << 16);
            ay += __uint_as_float(r.x & 0xffff0000u);
            az += __uint_as_float(r.y << 16);
            aw += __uint_as_float(r.y & 0xffff0000u);
        }
        id = idn;
    }
    ax += __shfl_xor(ax, 16); ay += __shfl_xor(ay, 16);
    az += __shfl_xor(az, 16); aw += __shfl_xor(aw, 16);
    ax += __shfl_xor(ax, 32); ay += __shfl_xor(ay, 32);
    az += __shfl_xor(az, 32); aw += __shfl_xor(aw, 32);

    if (g == 0) {
        float inv = 1.0f / fmaxf((float)cnt, 1.0f);
        float4 vr = ((const float4*)v)[(size_t)node * 16 + t4];
        float4 o;
        o.x = ax * inv + vr.x; o.y = ay * inv + vr.y;
        o.z = az * inv + vr.z; o.w = aw * inv + vr.w;
        ((float4*)sh[slot])[t4] = o;
    }
    // intra-wave LDS dependency: compiler orders via lgkmcnt; no barrier.

    int pq = f >> 5, c = (f >> 2) & 7, kp = f & 3;
    const float* W = pq ? sWr2 : sWl2;
    float a2 = 0.f;
    #pragma unroll
    for (int kk = 0; kk < 16; ++kk) {
        int k = kp * 16 + kk;
        a2 += sh[slot][k] * W[k * 9 + c];
    }
    a2 += __shfl_xor(a2, 1);
    a2 += __shfl_xor(a2, 2);
    if (kp == 0) {
        if (pq == 0) p[(size_t)node * 8 + c] = a2;
        else         q[(size_t)node * 8 + c] = a2;
    }
}

// ---------------------------------------------------------------------------
// Layer-2 gather-mean of p + epilogue. 2 nodes per wave.
// ---------------------------------------------------------------------------
__global__ __launch_bounds__(256) void k_final(
        const float* __restrict__ pv,
        const float* __restrict__ qv,
        const int* __restrict__ counts,
        const int* __restrict__ offsets,
        const unsigned short* __restrict__ sorted_src,
        const float* __restrict__ bl2,
        float* __restrict__ out,
        int nNodes) {
    int tid  = threadIdx.x;
    int wave = tid >> 6, lane = tid & 63;
    int half = lane >> 5;
    int eg   = (lane >> 3) & 3;
    int c    = lane & 7;
    int node = blockIdx.x * 8 + wave * 2 + half;
    if (node >= nNodes) return;
    int cnt = counts[node], off = offsets[node];
    float acc = 0.f;
    for (int base = 0; base < cnt; base += 4) {
        int e = base + eg;
        if (e < cnt) {
            int s = (int)sorted_src[off + e];
            acc += pv[(size_t)s * 8 + c];
        }
    }
    acc += __shfl_xor(acc, 8);
    acc += __shfl_xor(acc, 16);
    if (eg == 0) {
        float inv = 1.0f / fmaxf((float)cnt, 1.0f);
        out[(size_t)node * 8 + c] = acc * inv + qv[(size_t)node * 8 + c] + bl2[c];
    }
}

static inline size_t align256(size_t v) { return (v + 255) & ~(size_t)255; }

extern "C" void kernel_launch(void* const* d_in, const int* in_sizes, int n_in,
                              void* d_out, int out_size, void* d_ws, size_t ws_size,
                              hipStream_t stream) {
    const float* embeds = (const float*)d_in[0];
    const int*   ei     = (const int*)d_in[1];
    const float* Wl1    = (const float*)d_in[2];
    const float* bl1    = (const float*)d_in[3];
    const float* Wr1    = (const float*)d_in[4];
    const float* Wl2    = (const float*)d_in[5];
    const float* bl2    = (const float*)d_in[6];
    const float* Wr2    = (const float*)d_in[7];

    const int N = in_sizes[0] / N_FEATS;           // 50000
    const int E = in_sizes[1] / 2;                 // 800000
    const int* src = ei;
    const int* dst = ei + E;

    const int NBKT = (N + 255) >> NBKT_SHIFT;      // 196 coarse buckets
    const int NB1  = (E + EPB1 - 1) / EPB1;        // 196 phase-1 blocks
    const int M    = NBKT * NB1;                   // 38416 hist-matrix entries
    const int NBs  = (M + 255) / 256;              // 151 scan blocks

    // workspace layout (pairs aliases u: pairs dead before k_gemm writes u)
    char* ws = (char*)d_ws;
    size_t off = 0;
    int*            counts     = (int*)(ws + off); off += align256((size_t)N * sizeof(int));
    int*            offsets    = (int*)(ws + off); off += align256((size_t)N * sizeof(int));
    int*            partials   = (int*)(ws + off); off += align256((size_t)256 * sizeof(int));
    int*            H          = (int*)(ws + off); off += align256((size_t)M * sizeof(int));
    int*            HO         = (int*)(ws + off); off += align256((size_t)M * sizeof(int));
    unsigned short* sorted_src = (unsigned short*)(ws + off);
    off += align256((size_t)E * sizeof(unsigned short));
    unsigned*       u          = (unsigned*)(ws + off);         // bf16 u: N*64*2 B
    unsigned*       pairs      = (unsigned*)(ws + off);         // aliases u
    {
        size_t usz = (size_t)N * 64 * 2, psz = (size_t)E * sizeof(unsigned);
        off += align256(usz > psz ? usz : psz);
    }
    float*          v          = (float*)(ws + off); off += align256((size_t)N * 64 * sizeof(float));
    float*          p          = (float*)(ws + off); off += align256((size_t)N * 8 * sizeof(float));
    float*          q          = (float*)(ws + off); off += align256((size_t)N * 8 * sizeof(float));
    (void)ws_size;

    // CSR build: coarse hist -> scan -> multisplit -> per-bucket counting sort
    k_chist<<<NB1, 256, 0, stream>>>(dst, H, E, NBKT, NB1);
    k_partial<<<NBs, 256, 0, stream>>>(H, partials, M);
    k_offsets2<<<NBs, 256, 0, stream>>>(H, partials, HO, M);
    k_split<<<NB1, 256, 0, stream>>>(src, dst, HO, pairs, E, NBKT, NB1);
    k_fsort<<<NBKT, 256, 0, stream>>>(pairs, HO, counts, offsets, sorted_src,
                                      E, N, NBKT, NB1);
    // dense projections (after k_fsort: u aliases pairs)
    {
        int blocks = (N + 63) / 64;
        k_gemm<<<blocks, 256, 0, stream>>>(embeds, Wl1, bl1, Wr1, u, v, N);
    }
    {   // gather-mean(u) + v -> p,q
        int blocks = (N + 3) / 4;
        k_gather1<<<blocks, 256, 0, stream>>>(u, v, counts, offsets, sorted_src,
                                              Wl2, Wr2, p, q, N);
    }
    {   // layer-2 gather + epilogue
        int blocks = (N + 7) / 8;
        k_final<<<blocks, 256, 0, stream>>>(p, q, counts, offsets, sorted_src,
                                            bl2, (float*)d_out, N);
    }
}

// Round 10
// 100.526 us; speedup vs baseline: 1.4053x; 1.4053x over previous
//
#include <hip/hip_runtime.h>
#include <hip/hip_bf16.h>
#include <cstddef>

#define N_FEATS 64
#define NBKT_SHIFT 8      // coarse bucket = dst >> 8  (256 nodes per bucket)
#define EPB1 4096         // edges per phase-1 block
// NOTE: packing requires N <= 65536 (src fits u16 after shift). Here N = 50000.

typedef __attribute__((ext_vector_type(8))) short bf16x8;
typedef __attribute__((ext_vector_type(4))) float f32x4;

// round-to-nearest-even f32 -> bf16 bits
__device__ __forceinline__ unsigned f2bf(float f) {
    unsigned x = __float_as_uint(f);
    return (x + 0x7fffu + ((x >> 16) & 1u)) >> 16;
}

// ---------------------------------------------------------------------------
// Phase 1a: per-block coarse histogram -> H[bucket][block]  (bucket-major)
// ---------------------------------------------------------------------------
__global__ __launch_bounds__(256) void k_chist(const int* __restrict__ dst,
                                               int* __restrict__ H,
                                               int nEdges, int nbkt, int nb1) {
    __shared__ int lh[256];
    int tid = threadIdx.x, blk = blockIdx.x;
    lh[tid] = 0;
    __syncthreads();
    int base = blk * EPB1;
    #pragma unroll
    for (int j = 0; j < EPB1 / 256; ++j) {
        int e = base + j * 256 + tid;
        if (e < nEdges) atomicAdd(&lh[((unsigned)dst[e]) >> NBKT_SHIFT], 1);
    }
    __syncthreads();
    if (tid < nbkt) H[tid * nb1 + blk] = lh[tid];
}

// ---------------------------------------------------------------------------
// Scan: per-block partials, then per-block exclusive scan deriving its own
// base from the partials (no root kernel).
// ---------------------------------------------------------------------------
__global__ __launch_bounds__(256) void k_partial(const int* __restrict__ in,
                                                 int* __restrict__ partials, int n) {
    __shared__ int sdata[256];
    int tid = threadIdx.x;
    int i = blockIdx.x * 256 + tid;
    sdata[tid] = (i < n) ? in[i] : 0;
    __syncthreads();
    for (int s = 128; s > 0; s >>= 1) {
        if (tid < s) sdata[tid] += sdata[tid + s];
        __syncthreads();
    }
    if (tid == 0) partials[blockIdx.x] = sdata[0];
}

__global__ __launch_bounds__(256) void k_offsets2(const int* __restrict__ in,
                                                  const int* __restrict__ partials,
                                                  int* __restrict__ out, int n) {
    __shared__ int sdata[256];
    __shared__ int sbase[256];
    int tid = threadIdx.x;
    int i = blockIdx.x * 256 + tid;
    int b = 0;
    for (int j = tid; j < blockIdx.x; j += 256) b += partials[j];
    sbase[tid] = b;
    int v = (i < n) ? in[i] : 0;
    sdata[tid] = v;
    __syncthreads();
    for (int s = 128; s > 0; s >>= 1) {
        if (tid < s) sbase[tid] += sbase[tid + s];
        __syncthreads();
    }
    for (int d = 1; d < 256; d <<= 1) {
        int t = (tid >= d) ? sdata[tid - d] : 0;
        __syncthreads();
        sdata[tid] += t;
        __syncthreads();
    }
    int excl = sdata[tid] - v + sbase[0];
    if (i < n) out[i] = excl;
}

// ---------------------------------------------------------------------------
// Phase 1b: multisplit -> packed pairs (src<<8 | dst&255), grouped by coarse
// bucket; per-(bucket,block) cells contiguous; cursors in LDS.
// ---------------------------------------------------------------------------
__global__ __launch_bounds__(256) void k_split(const int* __restrict__ src,
                                               const int* __restrict__ dst,
                                               const int* __restrict__ HO,
                                               unsigned* __restrict__ pairs,
                                               int nEdges, int nbkt, int nb1) {
    __shared__ int cur[256];
    int tid = threadIdx.x, blk = blockIdx.x;
    if (tid < nbkt) cur[tid] = HO[tid * nb1 + blk];
    __syncthreads();
    int base = blk * EPB1;
    #pragma unroll
    for (int j = 0; j < EPB1 / 256; ++j) {
        int e = base + j * 256 + tid;
        if (e < nEdges) {
            unsigned d = (unsigned)dst[e];
            int pos = atomicAdd(&cur[d >> NBKT_SHIFT], 1);
            pairs[pos] = ((unsigned)src[e] << 8) | (d & 255u);
        }
    }
}

// ---------------------------------------------------------------------------
// Phase 2: one block per coarse bucket; counting sort by dst&255 in LDS.
// Emits counts[], offsets[], sorted_src[] (u16) — block-region-local writes.
// ---------------------------------------------------------------------------
__global__ __launch_bounds__(256) void k_fsort(const unsigned* __restrict__ pairs,
                                               const int* __restrict__ HO,
                                               int* __restrict__ counts,
                                               int* __restrict__ offsets,
                                               unsigned short* __restrict__ sorted_src,
                                               int nEdges, int nNodes,
                                               int nbkt, int nb1) {
    __shared__ int cnt[256];
    __shared__ int scanbuf[256];
    __shared__ int cur[256];
    int tid = threadIdx.x, b = blockIdx.x;
    int bStart = HO[b * nb1];
    int bEnd = (b + 1 < nbkt) ? HO[(b + 1) * nb1] : nEdges;
    cnt[tid] = 0;
    __syncthreads();
    for (int e = bStart + tid; e < bEnd; e += 256) {
        atomicAdd(&cnt[pairs[e] & 255u], 1);
    }
    __syncthreads();
    int v = cnt[tid];
    scanbuf[tid] = v;
    __syncthreads();
    for (int d = 1; d < 256; d <<= 1) {
        int t = (tid >= d) ? scanbuf[tid - d] : 0;
        __syncthreads();
        scanbuf[tid] += t;
        __syncthreads();
    }
    int excl = scanbuf[tid] - v;
    int node = (b << NBKT_SHIFT) + tid;
    if (node < nNodes) { counts[node] = v; offsets[node] = bStart + excl; }
    cur[tid] = bStart + excl;
    __syncthreads();
    for (int e = bStart + tid; e < bEnd; e += 256) {
        unsigned pr = pairs[e];
        int pos = atomicAdd(&cur[pr & 255u], 1);
        sorted_src[pos] = (unsigned short)(pr >> 8);
    }
}

// ---------------------------------------------------------------------------
// Dense projections via MFMA:  u = X@Wl1 (bf16 out),  v = X@Wr1 + b (f32 out).
// Inputs rounded to bf16; f32 accumulate in matrix cores.
// Block = 4 waves; wave w owns 16-feature column fbase = w*16 of BOTH outputs.
// B-frags (weights) live in 16 VGPRs per wave, loaded once. Per 64-node strip:
// 4 node-tiles x {2 MFMA for u, 2 MFMA for v} (K=64 split in two K=32 halves).
// Fragment layouts (m89-verified): A row=lane&15, k=8*(lane>>4)+i (contiguous);
// B col=lane&15, same k; C/D col=lane&15, row=(lane>>4)*4+reg.
// ---------------------------------------------------------------------------
__global__ __launch_bounds__(256) void k_gemm(
        const float* __restrict__ x,
        const float* __restrict__ Wl1,
        const float* __restrict__ bl1,
        const float* __restrict__ Wr1,
        unsigned short* __restrict__ u,   // bf16 [N][64]
        float* __restrict__ v,            // f32  [N][64]
        int nNodes, int nStrips) {
    int tid = threadIdx.x;
    int w  = tid >> 6;
    int l  = tid & 63;
    int fc = l & 15;        // feature col within tile
    int kg = l >> 4;        // k-group (rows of B frag / node-row group of D)
    int fbase = w * 16;

    // B fragments: element i -> k = kh*32 + kg*8 + i, feature = fbase+fc
    bf16x8 bu[2], bv[2];
    #pragma unroll
    for (int kh = 0; kh < 2; ++kh) {
        #pragma unroll
        for (int i = 0; i < 8; ++i) {
            int k = kh * 32 + kg * 8 + i;
            bu[kh][i] = (short)f2bf(Wl1[k * 64 + fbase + fc]);
            bv[kh][i] = (short)f2bf(Wr1[k * 64 + fbase + fc]);
        }
    }
    float bias = bl1[fbase + fc];

    for (int strip = blockIdx.x; strip < nStrips; strip += gridDim.x) {
        int node0 = strip * 64;
        #pragma unroll
        for (int nt = 0; nt < 4; ++nt) {
            int arow = node0 + nt * 16 + fc;               // A-row this lane loads
            int ar = (arow < nNodes) ? arow : (nNodes - 1);
            const float* xp = x + (size_t)ar * 64 + kg * 8;
            float4 xa = *(const float4*)(xp);
            float4 xb = *(const float4*)(xp + 4);
            float4 xc = *(const float4*)(xp + 32);
            float4 xd = *(const float4*)(xp + 36);
            bf16x8 a0, a1;
            a0[0]=(short)f2bf(xa.x); a0[1]=(short)f2bf(xa.y);
            a0[2]=(short)f2bf(xa.z); a0[3]=(short)f2bf(xa.w);
            a0[4]=(short)f2bf(xb.x); a0[5]=(short)f2bf(xb.y);
            a0[6]=(short)f2bf(xb.z); a0[7]=(short)f2bf(xb.w);
            a1[0]=(short)f2bf(xc.x); a1[1]=(short)f2bf(xc.y);
            a1[2]=(short)f2bf(xc.z); a1[3]=(short)f2bf(xc.w);
            a1[4]=(short)f2bf(xd.x); a1[5]=(short)f2bf(xd.y);
            a1[6]=(short)f2bf(xd.z); a1[7]=(short)f2bf(xd.w);

            f32x4 aU = {0.f, 0.f, 0.f, 0.f};
            f32x4 aV = {0.f, 0.f, 0.f, 0.f};
            aU = __builtin_amdgcn_mfma_f32_16x16x32_bf16(a0, bu[0], aU, 0, 0, 0);
            aU = __builtin_amdgcn_mfma_f32_16x16x32_bf16(a1, bu[1], aU, 0, 0, 0);
            aV = __builtin_amdgcn_mfma_f32_16x16x32_bf16(a0, bv[0], aV, 0, 0, 0);
            aV = __builtin_amdgcn_mfma_f32_16x16x32_bf16(a1, bv[1], aV, 0, 0, 0);

            #pragma unroll
            for (int r = 0; r < 4; ++r) {
                int node = node0 + nt * 16 + kg * 4 + r;   // D row
                if (node < nNodes) {
                    u[(size_t)node * 64 + fbase + fc] = (unsigned short)f2bf(aU[r]);
                    v[(size_t)node * 64 + fbase + fc] = aV[r] + bias;
                }
            }
        }
    }
}

// ---------------------------------------------------------------------------
// h = mean-gather(u: bf16) + v;  p = h@Wl2; q = h@Wr2.
// 1 node/wave; 16 lanes x 8B per u-row, 4 edge-groups in parallel.
// ---------------------------------------------------------------------------
__global__ __launch_bounds__(256) void k_gather1(
        const unsigned* __restrict__ u,
        const float* __restrict__ v,
        const int* __restrict__ counts,
        const int* __restrict__ offsets,
        const unsigned short* __restrict__ sorted_src,
        const float* __restrict__ Wl2,
        const float* __restrict__ Wr2,
        float* __restrict__ p,
        float* __restrict__ q,
        int nNodes) {
    __shared__ float sWl2[64 * 9];
    __shared__ float sWr2[64 * 9];
    __shared__ float sh[4][64];

    int tid = threadIdx.x;
    for (int i = tid; i < 64 * 8; i += 256) {
        int k = i >> 3, c = i & 7;
        sWl2[k * 9 + c] = Wl2[i];
        sWr2[k * 9 + c] = Wr2[i];
    }
    __syncthreads();

    int slot = tid >> 6;
    int f    = tid & 63;
    int g    = f >> 4;
    int t4   = f & 15;
    const uint2* uv2 = (const uint2*)u;

    int node = blockIdx.x * 4 + slot;
    if (node >= nNodes) return;
    int cnt = counts[node];
    int off = offsets[node];

    float ax = 0.f, ay = 0.f, az = 0.f, aw = 0.f;
    int id = (g < cnt) ? (int)sorted_src[off + g] : -1;
    for (int base = 0; base < cnt; base += 4) {
        int en  = base + 4 + g;
        int idn = (en < cnt) ? (int)sorted_src[off + en] : -1;
        if (id >= 0) {
            uint2 r = uv2[(size_t)id * 16 + t4];
            ax += __uint_as_float(r.x << 16);
            ay += __uint_as_float(r.x & 0xffff0000u);
            az += __uint_as_float(r.y << 16);
            aw += __uint_as_float(r.y & 0xffff0000u);
        }
        id = idn;
    }
    ax += __shfl_xor(ax, 16); ay += __shfl_xor(ay, 16);
    az += __shfl_xor(az, 16); aw += __shfl_xor(aw, 16);
    ax += __shfl_xor(ax, 32); ay += __shfl_xor(ay, 32);
    az += __shfl_xor(az, 32); aw += __shfl_xor(aw, 32);

    if (g == 0) {
        float inv = 1.0f / fmaxf((float)cnt, 1.0f);
        float4 vr = ((const float4*)v)[(size_t)node * 16 + t4];
        float4 o;
        o.x = ax * inv + vr.x; o.y = ay * inv + vr.y;
        o.z = az * inv + vr.z; o.w = aw * inv + vr.w;
        ((float4*)sh[slot])[t4] = o;
    }
    // intra-wave LDS dependency: compiler orders via lgkmcnt; no barrier.

    int pq = f >> 5, c = (f >> 2) & 7, kp = f & 3;
    const float* W = pq ? sWr2 : sWl2;
    float a2 = 0.f;
    #pragma unroll
    for (int kk = 0; kk < 16; ++kk) {
        int k = kp * 16 + kk;
        a2 += sh[slot][k] * W[k * 9 + c];
    }
    a2 += __shfl_xor(a2, 1);
    a2 += __shfl_xor(a2, 2);
    if (kp == 0) {
        if (pq == 0) p[(size_t)node * 8 + c] = a2;
        else         q[(size_t)node * 8 + c] = a2;
    }
}

// ---------------------------------------------------------------------------
// Layer-2 gather-mean of p + epilogue. 2 nodes per wave.
// ---------------------------------------------------------------------------
__global__ __launch_bounds__(256) void k_final(
        const float* __restrict__ pv,
        const float* __restrict__ qv,
        const int* __restrict__ counts,
        const int* __restrict__ offsets,
        const unsigned short* __restrict__ sorted_src,
        const float* __restrict__ bl2,
        float* __restrict__ out,
        int nNodes) {
    int tid  = threadIdx.x;
    int wave = tid >> 6, lane = tid & 63;
    int half = lane >> 5;
    int eg   = (lane >> 3) & 3;
    int c    = lane & 7;
    int node = blockIdx.x * 8 + wave * 2 + half;
    if (node >= nNodes) return;
    int cnt = counts[node], off = offsets[node];
    float acc = 0.f;
    for (int base = 0; base < cnt; base += 4) {
        int e = base + eg;
        if (e < cnt) {
            int s = (int)sorted_src[off + e];
            acc += pv[(size_t)s * 8 + c];
        }
    }
    acc += __shfl_xor(acc, 8);
    acc += __shfl_xor(acc, 16);
    if (eg == 0) {
        float inv = 1.0f / fmaxf((float)cnt, 1.0f);
        out[(size_t)node * 8 + c] = acc * inv + qv[(size_t)node * 8 + c] + bl2[c];
    }
}

static inline size_t align256(size_t v) { return (v + 255) & ~(size_t)255; }

extern "C" void kernel_launch(void* const* d_in, const int* in_sizes, int n_in,
                              void* d_out, int out_size, void* d_ws, size_t ws_size,
                              hipStream_t stream) {
    const float* embeds = (const float*)d_in[0];
    const int*   ei     = (const int*)d_in[1];
    const float* Wl1    = (const float*)d_in[2];
    const float* bl1    = (const float*)d_in[3];
    const float* Wr1    = (const float*)d_in[4];
    const float* Wl2    = (const float*)d_in[5];
    const float* bl2    = (const float*)d_in[6];
    const float* Wr2    = (const float*)d_in[7];

    const int N = in_sizes[0] / N_FEATS;           // 50000
    const int E = in_sizes[1] / 2;                 // 800000
    const int* src = ei;
    const int* dst = ei + E;

    const int NBKT = (N + 255) >> NBKT_SHIFT;      // 196 coarse buckets
    const int NB1  = (E + EPB1 - 1) / EPB1;        // 196 phase-1 blocks
    const int M    = NBKT * NB1;                   // 38416 hist-matrix entries
    const int NBs  = (M + 255) / 256;              // 151 scan blocks
    const int NSTRIPS = (N + 63) / 64;             // 782 gemm strips

    // workspace layout (pairs aliases u: pairs dead before k_gemm writes u)
    char* ws = (char*)d_ws;
    size_t off = 0;
    int*            counts     = (int*)(ws + off); off += align256((size_t)N * sizeof(int));
    int*            offsets    = (int*)(ws + off); off += align256((size_t)N * sizeof(int));
    int*            partials   = (int*)(ws + off); off += align256((size_t)256 * sizeof(int));
    int*            H          = (int*)(ws + off); off += align256((size_t)M * sizeof(int));
    int*            HO         = (int*)(ws + off); off += align256((size_t)M * sizeof(int));
    unsigned short* sorted_src = (unsigned short*)(ws + off);
    off += align256((size_t)E * sizeof(unsigned short));
    unsigned*       u          = (unsigned*)(ws + off);         // bf16 u: N*64*2 B
    unsigned*       pairs      = (unsigned*)(ws + off);         // aliases u
    {
        size_t usz = (size_t)N * 64 * 2, psz = (size_t)E * sizeof(unsigned);
        off += align256(usz > psz ? usz : psz);
    }
    float*          v          = (float*)(ws + off); off += align256((size_t)N * 64 * sizeof(float));
    float*          p          = (float*)(ws + off); off += align256((size_t)N * 8 * sizeof(float));
    float*          q          = (float*)(ws + off); off += align256((size_t)N * 8 * sizeof(float));
    (void)ws_size;

    // CSR build: coarse hist -> scan -> multisplit -> per-bucket counting sort
    k_chist<<<NB1, 256, 0, stream>>>(dst, H, E, NBKT, NB1);
    k_partial<<<NBs, 256, 0, stream>>>(H, partials, M);
    k_offsets2<<<NBs, 256, 0, stream>>>(H, partials, HO, M);
    k_split<<<NB1, 256, 0, stream>>>(src, dst, HO, pairs, E, NBKT, NB1);
    k_fsort<<<NBKT, 256, 0, stream>>>(pairs, HO, counts, offsets, sorted_src,
                                      E, N, NBKT, NB1);
    // dense projections via MFMA (after k_fsort: u aliases pairs)
    k_gemm<<<NSTRIPS, 256, 0, stream>>>(embeds, Wl1, bl1, Wr1,
                                        (unsigned short*)u, v, N, NSTRIPS);
    {   // gather-mean(u) + v -> p,q
        int blocks = (N + 3) / 4;
        k_gather1<<<blocks, 256, 0, stream>>>(u, v, counts, offsets, sorted_src,
                                              Wl2, Wr2, p, q, N);
    }
    {   // layer-2 gather + epilogue
        int blocks = (N + 7) / 8;
        k_final<<<blocks, 256, 0, stream>>>(p, q, counts, offsets, sorted_src,
                                            bl2, (float*)d_out, N);
    }
}

// Round 12
// 92.358 us; speedup vs baseline: 1.5296x; 1.0884x over previous
//
#include <hip/hip_runtime.h>
#include <hip/hip_bf16.h>
#include <cstddef>

#define N_FEATS 64
#define NBKT_SHIFT 8      // coarse bucket = dst >> 8  (256 nodes per bucket)
#define EPB1 4096         // edges per phase-1 block
// NOTE: packing requires N <= 65536 (src fits u16 after shift). Here N = 50000.

typedef __attribute__((ext_vector_type(8))) short bf16x8;
typedef __attribute__((ext_vector_type(4))) float f32x4;

// round-to-nearest-even f32 -> bf16 bits
__device__ __forceinline__ unsigned f2bf(float f) {
    unsigned x = __float_as_uint(f);
    return (x + 0x7fffu + ((x >> 16) & 1u)) >> 16;
}

// ---------------------------------------------------------------------------
// Phase 1a: per-block coarse histogram -> H[bucket][block]; the extra block
// (blk == nb1) computes the combined weights:
//   Wc[64][32] = [Wl1@Wl2 | Wl1@Wr2 | Wr1@Wl2 | Wr1@Wr2]  (bf16)
//   bvec[16]   = [b@Wl2 | b@Wr2 + bl2]                      (f32)
// ---------------------------------------------------------------------------
__global__ __launch_bounds__(256) void k_chist_wcomb(
        const int* __restrict__ dst, int* __restrict__ H,
        const float* __restrict__ Wl1, const float* __restrict__ bl1,
        const float* __restrict__ Wr1, const float* __restrict__ Wl2,
        const float* __restrict__ bl2, const float* __restrict__ Wr2,
        unsigned short* __restrict__ Wc, float* __restrict__ bvec,
        int nEdges, int nbkt, int nb1) {
    __shared__ int lh[256];
    int tid = threadIdx.x, blk = blockIdx.x;
    if (blk < nb1) {
        lh[tid] = 0;
        __syncthreads();
        int base = blk * EPB1;
        #pragma unroll
        for (int j = 0; j < EPB1 / 256; ++j) {
            int e = base + j * 256 + tid;
            if (e < nEdges) atomicAdd(&lh[((unsigned)dst[e]) >> NBKT_SHIFT], 1);
        }
        __syncthreads();
        if (tid < nbkt) H[tid * nb1 + blk] = lh[tid];
    } else {
        // weight combine: thread -> row k = tid&63, quadrant jg = tid>>6
        int k = tid & 63, jg = tid >> 6;
        const float* W1 = (jg < 2) ? Wl1 : Wr1;
        const float* W2 = (jg & 1) ? Wr2 : Wl2;
        float acc[8] = {0.f,0.f,0.f,0.f,0.f,0.f,0.f,0.f};
        for (int m = 0; m < 64; ++m) {
            float w1 = W1[k * 64 + m];
            #pragma unroll
            for (int jj = 0; jj < 8; ++jj) acc[jj] += w1 * W2[m * 8 + jj];
        }
        #pragma unroll
        for (int jj = 0; jj < 8; ++jj)
            Wc[k * 32 + jg * 8 + jj] = (unsigned short)f2bf(acc[jj]);
        if (tid < 16) {
            int j2 = tid;
            const float* W2b = (j2 < 8) ? Wl2 : Wr2;
            float a = 0.f;
            for (int m = 0; m < 64; ++m) a += bl1[m] * W2b[m * 8 + (j2 & 7)];
            if (j2 >= 8) a += bl2[j2 - 8];
            bvec[j2] = a;
        }
    }
}

// ---------------------------------------------------------------------------
// Exclusive scan of H -> HO; each block derives its own base by summing the
// raw input over all preceding blocks (L2-hot).
// ---------------------------------------------------------------------------
__global__ __launch_bounds__(256) void k_offsets2(const int* __restrict__ in,
                                                  int* __restrict__ out, int n) {
    __shared__ int sdata[256];
    __shared__ int sbase[256];
    int tid = threadIdx.x;
    int i = blockIdx.x * 256 + tid;
    int lim = blockIdx.x * 256;
    int b = 0;
    for (int j = tid; j < lim; j += 256) b += in[j];
    sbase[tid] = b;
    int v = (i < n) ? in[i] : 0;
    sdata[tid] = v;
    __syncthreads();
    for (int s = 128; s > 0; s >>= 1) {
        if (tid < s) sbase[tid] += sbase[tid + s];
        __syncthreads();
    }
    for (int d = 1; d < 256; d <<= 1) {
        int t = (tid >= d) ? sdata[tid - d] : 0;
        __syncthreads();
        sdata[tid] += t;
        __syncthreads();
    }
    int excl = sdata[tid] - v + sbase[0];
    if (i < n) out[i] = excl;
}

// ---------------------------------------------------------------------------
// Phase 1b: multisplit -> packed pairs (src<<8 | dst&255), grouped by coarse
// bucket; per-(bucket,block) cells contiguous; cursors in LDS.
// ---------------------------------------------------------------------------
__global__ __launch_bounds__(256) void k_split(const int* __restrict__ src,
                                               const int* __restrict__ dst,
                                               const int* __restrict__ HO,
                                               unsigned* __restrict__ pairs,
                                               int nEdges, int nbkt, int nb1) {
    __shared__ int cur[256];
    int tid = threadIdx.x, blk = blockIdx.x;
    if (tid < nbkt) cur[tid] = HO[tid * nb1 + blk];
    __syncthreads();
    int base = blk * EPB1;
    #pragma unroll
    for (int j = 0; j < EPB1 / 256; ++j) {
        int e = base + j * 256 + tid;
        if (e < nEdges) {
            unsigned d = (unsigned)dst[e];
            int pos = atomicAdd(&cur[d >> NBKT_SHIFT], 1);
            pairs[pos] = ((unsigned)src[e] << 8) | (d & 255u);
        }
    }
}

// ---------------------------------------------------------------------------
// Fused dispatch: blocks < nbkt do the per-bucket counting sort (fsort);
// blocks >= nbkt run the MFMA GEMM  Y = X@Wc -> G (bf16 s|s'), T (f32 t|t').
// The two halves are independent (GEMM needs no CSR data).
// ---------------------------------------------------------------------------
__global__ __launch_bounds__(256) void k_fsort_gemm(
        const unsigned* __restrict__ pairs,
        const int* __restrict__ HO,
        int* __restrict__ counts,
        int* __restrict__ offsets,
        unsigned short* __restrict__ sorted_src,
        int nEdges, int nNodes, int nbkt, int nb1,
        const float* __restrict__ x,
        const unsigned short* __restrict__ Wc,
        const float* __restrict__ bvec,
        unsigned short* __restrict__ G,   // bf16 [N][16] = [s|s']
        float* __restrict__ T,            // f32  [N][16] = [t|t'] (+bias)
        int nStrips) {
    __shared__ int cnt[256];
    __shared__ int scanbuf[256];
    __shared__ int cur[256];
    int tid = threadIdx.x, b = blockIdx.x;

    if (b < nbkt) {
        // ---- per-bucket counting sort ----
        int bStart = HO[b * nb1];
        int bEnd = (b + 1 < nbkt) ? HO[(b + 1) * nb1] : nEdges;
        cnt[tid] = 0;
        __syncthreads();
        for (int e = bStart + tid; e < bEnd; e += 256) {
            atomicAdd(&cnt[pairs[e] & 255u], 1);
        }
        __syncthreads();
        int v = cnt[tid];
        scanbuf[tid] = v;
        __syncthreads();
        for (int d = 1; d < 256; d <<= 1) {
            int t = (tid >= d) ? scanbuf[tid - d] : 0;
            __syncthreads();
            scanbuf[tid] += t;
            __syncthreads();
        }
        int excl = scanbuf[tid] - v;
        int node = (b << NBKT_SHIFT) + tid;
        if (node < nNodes) { counts[node] = v; offsets[node] = bStart + excl; }
        cur[tid] = bStart + excl;
        __syncthreads();
        for (int e = bStart + tid; e < bEnd; e += 256) {
            unsigned pr = pairs[e];
            int pos = atomicAdd(&cur[pr & 255u], 1);
            sorted_src[pos] = (unsigned short)(pr >> 8);
        }
        return;
    }

    // ---- MFMA GEMM: wave w handles node-subtile nt=w (16 nodes), 32 cols ----
    int w  = tid >> 6;
    int l  = tid & 63;
    int fc = l & 15;        // A-row / D-col within tile
    int kg = l >> 4;        // k-group
    bf16x8 bf[2][2];        // [col-tile][k-half]
    #pragma unroll
    for (int ct = 0; ct < 2; ++ct)
        #pragma unroll
        for (int kh = 0; kh < 2; ++kh)
            #pragma unroll
            for (int i = 0; i < 8; ++i) {
                int k = kh * 32 + kg * 8 + i;
                bf[ct][kh][i] = (short)Wc[k * 32 + ct * 16 + fc];
            }
    float bias = bvec[fc];

    for (int strip = b - nbkt; strip < nStrips; strip += gridDim.x - nbkt) {
        int node0 = strip * 64;
        int arow = node0 + w * 16 + fc;
        int ar = (arow < nNodes) ? arow : (nNodes - 1);
        const float* xp = x + (size_t)ar * 64 + kg * 8;
        float4 xa = *(const float4*)(xp);
        float4 xb = *(const float4*)(xp + 4);
        float4 xc = *(const float4*)(xp + 32);
        float4 xd = *(const float4*)(xp + 36);
        bf16x8 a0, a1;
        a0[0]=(short)f2bf(xa.x); a0[1]=(short)f2bf(xa.y);
        a0[2]=(short)f2bf(xa.z); a0[3]=(short)f2bf(xa.w);
        a0[4]=(short)f2bf(xb.x); a0[5]=(short)f2bf(xb.y);
        a0[6]=(short)f2bf(xb.z); a0[7]=(short)f2bf(xb.w);
        a1[0]=(short)f2bf(xc.x); a1[1]=(short)f2bf(xc.y);
        a1[2]=(short)f2bf(xc.z); a1[3]=(short)f2bf(xc.w);
        a1[4]=(short)f2bf(xd.x); a1[5]=(short)f2bf(xd.y);
        a1[6]=(short)f2bf(xd.z); a1[7]=(short)f2bf(xd.w);

        f32x4 d0 = {0.f, 0.f, 0.f, 0.f};
        f32x4 d1 = {0.f, 0.f, 0.f, 0.f};
        d0 = __builtin_amdgcn_mfma_f32_16x16x32_bf16(a0, bf[0][0], d0, 0, 0, 0);
        d0 = __builtin_amdgcn_mfma_f32_16x16x32_bf16(a1, bf[0][1], d0, 0, 0, 0);
        d1 = __builtin_amdgcn_mfma_f32_16x16x32_bf16(a0, bf[1][0], d1, 0, 0, 0);
        d1 = __builtin_amdgcn_mfma_f32_16x16x32_bf16(a1, bf[1][1], d1, 0, 0, 0);

        #pragma unroll
        for (int r = 0; r < 4; ++r) {
            int node = node0 + w * 16 + kg * 4 + r;
            if (node < nNodes) {
                G[(size_t)node * 16 + fc] = (unsigned short)f2bf(d0[r]);
                T[(size_t)node * 16 + fc] = d1[r] + bias;
            }
        }
    }
}

// ---------------------------------------------------------------------------
// p = mean-gather(s) + t  (-> bf16),  q = mean-gather(s') + t'  (-> f32).
// 1 node/wave; 8 edge-groups x 8 lanes x 4B (uint = 2 bf16) per G-row.
// ---------------------------------------------------------------------------
__global__ __launch_bounds__(256) void k_gather2(
        const unsigned* __restrict__ G,     // [N][8] uints
        const float* __restrict__ T,        // [N][16]
        const int* __restrict__ counts,
        const int* __restrict__ offsets,
        const unsigned short* __restrict__ ss,
        unsigned* __restrict__ pbf,         // [N][4] uints (8 bf16)
        float* __restrict__ q,              // [N][8]
        int nNodes) {
    int tid = threadIdx.x;
    int slot = tid >> 6, lane = tid & 63;
    int g = lane >> 3, t = lane & 7;
    int node = blockIdx.x * 4 + slot;
    if (node >= nNodes) return;
    int cnt = counts[node], off = offsets[node];
    float a0 = 0.f, a1 = 0.f;
    int id = (g < cnt) ? (int)ss[off + g] : -1;
    for (int base = 0; base < cnt; base += 8) {
        int en = base + 8 + g;
        int idn = (en < cnt) ? (int)ss[off + en] : -1;
        if (id >= 0) {
            unsigned r = G[(size_t)id * 8 + t];
            a0 += __uint_as_float(r << 16);
            a1 += __uint_as_float(r & 0xffff0000u);
        }
        id = idn;
    }
    a0 += __shfl_xor(a0, 8);  a1 += __shfl_xor(a1, 8);
    a0 += __shfl_xor(a0, 16); a1 += __shfl_xor(a1, 16);
    a0 += __shfl_xor(a0, 32); a1 += __shfl_xor(a1, 32);
    if (g == 0) {
        float inv = 1.0f / fmaxf((float)cnt, 1.0f);
        float2 tv = *(const float2*)&T[(size_t)node * 16 + 2 * t];
        float r0 = a0 * inv + tv.x;
        float r1 = a1 * inv + tv.y;
        if (t < 4) pbf[(size_t)node * 4 + t] = f2bf(r0) | (f2bf(r1) << 16);
        else ((float2*)q)[(size_t)node * 4 + (t - 4)] = make_float2(r0, r1);
    }
}

// ---------------------------------------------------------------------------
// out = mean-gather(p) + q.  1 node/wave; 16 edge-groups x 4 lanes x uint.
// ---------------------------------------------------------------------------
__global__ __launch_bounds__(256) void k_final(
        const unsigned* __restrict__ pbf,   // [N][4] uints (8 bf16)
        const float* __restrict__ q,        // [N][8]
        const int* __restrict__ counts,
        const int* __restrict__ offsets,
        const unsigned short* __restrict__ ss,
        float* __restrict__ out,
        int nNodes) {
    int tid = threadIdx.x;
    int slot = tid >> 6, lane = tid & 63;
    int eg = lane >> 2, t = lane & 3;
    int node = blockIdx.x * 4 + slot;
    if (node >= nNodes) return;
    int cnt = counts[node], off = offsets[node];
    float a0 = 0.f, a1 = 0.f;
    int id = (eg < cnt) ? (int)ss[off + eg] : -1;
    for (int base = 0; base < cnt; base += 16) {
        int en = base + 16 + eg;
        int idn = (en < cnt) ? (int)ss[off + en] : -1;
        if (id >= 0) {
            unsigned r = pbf[(size_t)id * 4 + t];
            a0 += __uint_as_float(r << 16);
            a1 += __uint_as_float(r & 0xffff0000u);
        }
        id = idn;
    }
    a0 += __shfl_xor(a0, 4);  a1 += __shfl_xor(a1, 4);
    a0 += __shfl_xor(a0, 8);  a1 += __shfl_xor(a1, 8);
    a0 += __shfl_xor(a0, 16); a1 += __shfl_xor(a1, 16);
    a0 += __shfl_xor(a0, 32); a1 += __shfl_xor(a1, 32);
    if (eg == 0) {
        float inv = 1.0f / fmaxf((float)cnt, 1.0f);
        float2 qv = ((const float2*)q)[(size_t)node * 4 + t];
        ((float2*)out)[(size_t)node * 4 + t] =
            make_float2(a0 * inv + qv.x, a1 * inv + qv.y);
    }
}

static inline size_t align256(size_t v) { return (v + 255) & ~(size_t)255; }

extern "C" void kernel_launch(void* const* d_in, const int* in_sizes, int n_in,
                              void* d_out, int out_size, void* d_ws, size_t ws_size,
                              hipStream_t stream) {
    const float* embeds = (const float*)d_in[0];
    const int*   ei     = (const int*)d_in[1];
    const float* Wl1    = (const float*)d_in[2];
    const float* bl1    = (const float*)d_in[3];
    const float* Wr1    = (const float*)d_in[4];
    const float* Wl2    = (const float*)d_in[5];
    const float* bl2    = (const float*)d_in[6];
    const float* Wr2    = (const float*)d_in[7];

    const int N = in_sizes[0] / N_FEATS;           // 50000
    const int E = in_sizes[1] / 2;                 // 800000
    const int* src = ei;
    const int* dst = ei + E;

    const int NBKT = (N + 255) >> NBKT_SHIFT;      // 196 coarse buckets
    const int NB1  = (E + EPB1 - 1) / EPB1;        // 196 phase-1 blocks
    const int M    = NBKT * NB1;                   // 38416 hist-matrix entries
    const int NBs  = (M + 255) / 256;              // 151 scan blocks
    const int NSTRIPS = (N + 63) / 64;             // 782 gemm strips

    // workspace layout
    char* ws = (char*)d_ws;
    size_t off = 0;
    int*            counts     = (int*)(ws + off); off += align256((size_t)N * sizeof(int));
    int*            offsets    = (int*)(ws + off); off += align256((size_t)N * sizeof(int));
    int*            H          = (int*)(ws + off); off += align256((size_t)M * sizeof(int));
    int*            HO         = (int*)(ws + off); off += align256((size_t)M * sizeof(int));
    unsigned short* sorted_src = (unsigned short*)(ws + off);
    off += align256((size_t)E * sizeof(unsigned short));
    unsigned short* Wc         = (unsigned short*)(ws + off); off += align256(64 * 32 * sizeof(unsigned short));
    float*          bvec       = (float*)(ws + off); off += align256(16 * sizeof(float));
    unsigned*       pairs      = (unsigned*)(ws + off); off += align256((size_t)E * sizeof(unsigned));
    unsigned*       G          = (unsigned*)(ws + off); off += align256((size_t)N * 16 * sizeof(unsigned short));
    float*          T          = (float*)(ws + off); off += align256((size_t)N * 16 * sizeof(float));
    unsigned*       pbf        = (unsigned*)(ws + off); off += align256((size_t)N * 4 * sizeof(unsigned));
    float*          q          = (float*)(ws + off); off += align256((size_t)N * 8 * sizeof(float));
    (void)ws_size;

    // 1. coarse histogram + weight combine (extra block)
    k_chist_wcomb<<<NB1 + 1, 256, 0, stream>>>(dst, H, Wl1, bl1, Wr1, Wl2, bl2,
                                               Wr2, Wc, bvec, E, NBKT, NB1);
    // 2. exclusive scan H -> HO (self-basing, no root/partial kernels)
    k_offsets2<<<NBs, 256, 0, stream>>>(H, HO, M);
    // 3. multisplit into coarse buckets
    k_split<<<NB1, 256, 0, stream>>>(src, dst, HO, pairs, E, NBKT, NB1);
    // 4. per-bucket counting sort || MFMA GEMM  Y = X@Wc
    k_fsort_gemm<<<NBKT + NSTRIPS, 256, 0, stream>>>(
        pairs, HO, counts, offsets, sorted_src, E, N, NBKT, NB1,
        embeds, Wc, bvec, (unsigned short*)G, T, NSTRIPS);
    // 5. p,q = mean-gather(G) + T
    k_gather2<<<(N + 3) / 4, 256, 0, stream>>>(G, T, counts, offsets, sorted_src,
                                               pbf, q, N);
    // 6. out = mean-gather(p) + q
    k_final<<<(N + 3) / 4, 256, 0, stream>>>(pbf, q, counts, offsets, sorted_src,
                                             (float*)d_out, N);
}